// Round 1
// baseline (891.254 us; speedup 1.0000x reference)
//
#include <hip/hip_runtime.h>
#include <math.h>

#define BB 16
#define NN 1024
#define VV 4096
#define TT 8
#define NG (BB*TT)   // 128 groups
#define KMAX 124     // max group size; Binomial(1024,1/16): mean 64, sigma 7.75 -> 124 is ~8 sigma

__device__ __forceinline__ float wave_max(float v){
  #pragma unroll
  for (int off = 32; off; off >>= 1) v = fmaxf(v, __shfl_down(v, off));
  return v;
}
__device__ __forceinline__ float wave_sum(float v){
  #pragma unroll
  for (int off = 32; off; off >>= 1) v += __shfl_down(v, off);
  return v;
}

// ---------------------------------------------------------------------------
// Normalize mask to int32[B*N] in ws. Harness may deliver numpy bool (1B/elem)
// or int32 (4B/elem). If int32, bytes 4i+1..4i+3 are 0 for ALL i (values are
// 0/1); if bool, ~half the probed bytes are 1 -> P(false detect) ~ 2^-4096.
// Probe only the first 16384 bytes (valid in both layouts).
__global__ __launch_bounds__(256) void k_mask(const unsigned char* __restrict__ raw,
                                              int* __restrict__ mnorm){
  __shared__ int nonzero_probe;
  int tid = threadIdx.x;
  if (tid == 0) nonzero_probe = 0;
  __syncthreads();
  int local = 0;
  for (int i = tid; i < 4096; i += 256)
    local |= raw[4*i+1] | raw[4*i+2] | raw[4*i+3];
  if (local) atomicOr(&nonzero_probe, 1);
  __syncthreads();
  bool bool_layout = (nonzero_probe != 0);
  for (int i = tid; i < BB*NN; i += 256){
    int v = bool_layout ? (int)raw[i] : ((const int*)raw)[i];
    mnorm[i] = (v != 0) ? 1 : 0;
  }
}

// ---------------------------------------------------------------------------
// Per-row logsumexp over V=4096, masked rows only. 256 thr * 16 elem (4xfloat4).
__global__ __launch_bounds__(256) void k_lse(const float* __restrict__ logits,
                                             const int* __restrict__ mask,
                                             float* __restrict__ lse){
  int row = blockIdx.x;
  if (mask[row] == 0) return;
  const float4* x = (const float4*)(logits + (size_t)row * VV);
  int tid = threadIdx.x;
  float4 a = x[tid], b = x[tid+256], c = x[tid+512], d = x[tid+768];
  float m = fmaxf(fmaxf(fmaxf(fmaxf(a.x,a.y),fmaxf(a.z,a.w)),
                        fmaxf(fmaxf(b.x,b.y),fmaxf(b.z,b.w))),
                  fmaxf(fmaxf(fmaxf(c.x,c.y),fmaxf(c.z,c.w)),
                        fmaxf(fmaxf(d.x,d.y),fmaxf(d.z,d.w))));
  __shared__ float red[8];
  float wm = wave_max(m);
  int wid = tid >> 6;
  if ((tid & 63) == 0) red[wid] = wm;
  __syncthreads();
  if (tid == 0) red[4] = fmaxf(fmaxf(red[0],red[1]), fmaxf(red[2],red[3]));
  __syncthreads();
  float M = red[4];
  float s = __expf(a.x-M)+__expf(a.y-M)+__expf(a.z-M)+__expf(a.w-M)
          + __expf(b.x-M)+__expf(b.y-M)+__expf(b.z-M)+__expf(b.w-M)
          + __expf(c.x-M)+__expf(c.y-M)+__expf(c.z-M)+__expf(c.w-M)
          + __expf(d.x-M)+__expf(d.y-M)+__expf(d.z-M)+__expf(d.w-M);
  float ws = wave_sum(s);
  __syncthreads();
  if ((tid & 63) == 0) red[wid] = ws;
  __syncthreads();
  if (tid == 0) lse[row] = M + __logf(red[0]+red[1]+red[2]+red[3]);
}

// ---------------------------------------------------------------------------
// Build (idx, gt) lists per (b, t) group via wave-ballot compaction.
__global__ __launch_bounds__(64) void k_group(const int* __restrict__ types,
                                              const int* __restrict__ mask,
                                              const int* __restrict__ gt,
                                              int* __restrict__ idxg,
                                              int* __restrict__ gtkg,
                                              int* __restrict__ kcnt){
  int g = blockIdx.x;
  int b = g >> 3, t = g & 7;
  int lane = threadIdx.x;
  int base = 0;
  for (int r = 0; r < NN/64; r++){
    int pos = r*64 + lane;
    int o = b*NN + pos;
    bool pred = (types[o] == t) && (mask[o] != 0);
    unsigned long long bal = __ballot(pred);
    int pre = __popcll(bal & ((1ull << lane) - 1ull));
    int dst = base + pre;
    if (pred && dst < KMAX){
      idxg[g*KMAX + dst] = pos;
      gtkg[g*KMAX + dst] = gt[o];
    }
    base += __popcll(bal);
  }
  if (lane == 0) kcnt[g] = (base > KMAX) ? KMAX : base;
}

// ---------------------------------------------------------------------------
// Jonker-Volgenant shortest-augmenting-path LAP per group (faithful port of
// the numpy reference, 1-based cols, virtual col 0). One wave per block;
// lane owns cols {lane+1, lane+65}. Cost C[i][j] = -logits[b, idx_i, g_j]
// (lse term is assignment-invariant, handled separately). Only the optimal
// VALUE is needed -> gval[g] = max-assignment sum of A = -min-assignment of C.
__global__ __launch_bounds__(64) void k_jv(const float* __restrict__ logits,
                                           const int* __restrict__ idxg,
                                           const int* __restrict__ gtkg,
                                           const int* __restrict__ kcnt,
                                           float* __restrict__ gval){
  __shared__ float Cm[KMAX][KMAX];     // 61504 B
  __shared__ float u_l[KMAX+1];        // row potentials (index by row 1..k)
  __shared__ int   p_l[KMAX+1];        // col -> row (1-based; 0 = unassigned)
  __shared__ int   way_l[KMAX+1];      // predecessor column on alternating path
  int g = blockIdx.x;
  int b = g >> 3;
  int lane = threadIdx.x;
  int k = kcnt[g];
  if (k > KMAX) k = KMAX;
  if (k == 0){ if (lane == 0) gval[g] = 0.f; return; }

  int col0 = lane + 1, col1 = lane + 65;
  int gc0 = (col0 <= k) ? gtkg[g*KMAX + col0 - 1] : 0;
  int gc1 = (col1 <= k) ? gtkg[g*KMAX + col1 - 1] : 0;
  for (int i = 0; i < k; i++){
    const float* rowp = logits + ((size_t)(b*NN + idxg[g*KMAX + i])) * VV;
    if (col0 <= k) Cm[i][col0-1] = -rowp[gc0];
    if (col1 <= k) Cm[i][col1-1] = -rowp[gc1];
  }
  if (col0 <= KMAX){ u_l[col0] = 0.f; p_l[col0] = 0; way_l[col0] = 0; }
  if (col1 <= KMAX){ u_l[col1] = 0.f; p_l[col1] = 0; way_l[col1] = 0; }
  if (lane == 0){ u_l[0] = 0.f; p_l[0] = 0; way_l[0] = 0; }
  float v0 = 0.f, v1 = 0.f;     // column potentials, register-resident
  __syncthreads();

  for (int i = 1; i <= k; i++){
    if (lane == 0) p_l[0] = i;
    float minv0 = INFINITY, minv1 = INFINITY;
    bool used0 = false, used1 = false;
    __syncthreads();                       // prev-row p_l/u_l writes + p_l[0]
    int pr0 = (col0 <= k) ? p_l[col0] : 0; // p is frozen during the scan
    int pr1 = (col1 <= k) ? p_l[col1] : 0;
    int j0 = 0;
    float u_i = 0.f;                       // u[i] accumulates delta each iter
    while (true){
      if (col0 == j0) used0 = true;
      if (col1 == j0) used1 = true;
      int i0 = p_l[j0];                    // broadcast LDS read
      float u_i0 = (j0 == 0) ? 0.f : u_l[i0];
      if (col0 <= k && !used0){
        float cur = Cm[i0-1][col0-1] - u_i0 - v0;
        if (cur < minv0){ minv0 = cur; way_l[col0] = j0; }
      }
      if (col1 <= k && !used1){
        float cur = Cm[i0-1][col1-1] - u_i0 - v1;
        if (cur < minv1){ minv1 = cur; way_l[col1] = j0; }
      }
      // argmin over free columns
      float mv = INFINITY; int mj = 0;
      if (col0 <= k && !used0){ mv = minv0; mj = col0; }
      if (col1 <= k && !used1 && minv1 < mv){ mv = minv1; mj = col1; }
      #pragma unroll
      for (int off = 32; off; off >>= 1){
        float ov = __shfl_down(mv, off);
        int   oj = __shfl_down(mj, off);
        if (ov < mv){ mv = ov; mj = oj; }
      }
      float delta = __shfl(mv, 0);
      int j1 = __shfl(mj, 0);
      // dual updates (ref: u[p[used]]+=d; v[used]-=d; minv[free]-=d)
      if (col0 <= k){ if (used0){ v0 -= delta; u_l[pr0] += delta; } else minv0 -= delta; }
      if (col1 <= k){ if (used1){ v1 -= delta; u_l[pr1] += delta; } else minv1 -= delta; }
      u_i += delta;                        // virtual col 0: u[p[0]] = u[i]
      j0 = j1;
      if (p_l[j0] == 0) break;
      __syncthreads();                     // u_l scatter-adds -> next-iter reads
    }
    if (lane == 0) u_l[i] = u_i;
    __syncthreads();                       // way_l lane-writes -> uniform walk
    // augment along predecessor chain (wave-uniform; lane 0 commits p)
    while (j0 != 0){
      int jw = way_l[j0];
      if (lane == 0) p_l[j0] = p_l[jw];
      j0 = jw;
    }
  }
  __syncthreads();
  float acc = 0.f;
  if (col0 <= k) acc += Cm[p_l[col0]-1][col0-1];
  if (col1 <= k) acc += Cm[p_l[col1]-1][col1-1];
  acc = wave_sum(acc);
  if (lane == 0) gval[g] = -acc;           // max-assignment value of A
}

// ---------------------------------------------------------------------------
// loss = (sum_masked lse - sum_g gval) / total_masked
__global__ __launch_bounds__(256) void k_final(const float* __restrict__ lse,
                                               const int* __restrict__ mask,
                                               const float* __restrict__ gval,
                                               float* __restrict__ out){
  __shared__ double sd[256];
  __shared__ double sg[256];
  __shared__ int    si[256];
  int tid = threadIdx.x;
  double s = 0.0, gs = 0.0; int c = 0;
  for (int i = tid; i < BB*NN; i += 256)
    if (mask[i]){ s += (double)lse[i]; c++; }
  for (int i = tid; i < NG; i += 256) gs += (double)gval[i];
  sd[tid] = s; sg[tid] = gs; si[tid] = c;
  __syncthreads();
  for (int off = 128; off; off >>= 1){
    if (tid < off){ sd[tid] += sd[tid+off]; sg[tid] += sg[tid+off]; si[tid] += si[tid+off]; }
    __syncthreads();
  }
  if (tid == 0) out[0] = (float)((sd[0] - sg[0]) / (double)si[0]);
}

extern "C" void kernel_launch(void* const* d_in, const int* in_sizes, int n_in,
                              void* d_out, int out_size, void* d_ws, size_t ws_size,
                              hipStream_t stream) {
  const float* logits = (const float*)d_in[0];
  const int*   gt     = (const int*)d_in[1];
  const int*   types  = (const int*)d_in[2];
  const unsigned char* maskraw = (const unsigned char*)d_in[3];
  float* out = (float*)d_out;

  char* w = (char*)d_ws;
  float* lse   = (float*)w;  w += (size_t)BB*NN*4;
  int*   mnorm = (int*)w;    w += (size_t)BB*NN*4;
  int*   idxg  = (int*)w;    w += (size_t)NG*KMAX*4;
  int*   gtkg  = (int*)w;    w += (size_t)NG*KMAX*4;
  int*   kcnt  = (int*)w;    w += 1024;
  float* gval  = (float*)w;  w += 1024;

  k_mask <<<1,      256, 0, stream>>>(maskraw, mnorm);
  k_lse  <<<BB*NN,  256, 0, stream>>>(logits, mnorm, lse);
  k_group<<<NG,      64, 0, stream>>>(types, mnorm, gt, idxg, gtkg, kcnt);
  k_jv   <<<NG,      64, 0, stream>>>(logits, idxg, gtkg, kcnt, gval);
  k_final<<<1,      256, 0, stream>>>(lse, mnorm, gval, out);
}

// Round 2
// 644.126 us; speedup vs baseline: 1.3837x; 1.3837x over previous
//
#include <hip/hip_runtime.h>
#include <math.h>

#define BB 16
#define NN 1024
#define VV 4096
#define TT 8
#define NG (BB*TT)   // 128 groups
#define KMAX 124     // max group size; Binomial(1024,1/16): mean 64, sigma 7.75 -> 124 is ~8 sigma
#define STRIDE 124

__device__ __forceinline__ float wave_max(float v){
  #pragma unroll
  for (int off = 32; off; off >>= 1) v = fmaxf(v, __shfl_down(v, off));
  return v;
}
__device__ __forceinline__ float wave_sum(float v){
  #pragma unroll
  for (int off = 32; off; off >>= 1) v += __shfl_down(v, off);
  return v;
}

// monotone float -> uint key (all finite values, no NaN)
__device__ __forceinline__ unsigned fkey(float f){
  unsigned b = __float_as_uint(f);
  return b ^ ((unsigned)((int)b >> 31) | 0x80000000u);
}

// 64-lane min-reduction via DPP (VALU-only). Result valid in lane 63.
__device__ __forceinline__ unsigned dpp_min64(unsigned x){
  unsigned t;
  t = (unsigned)__builtin_amdgcn_update_dpp(-1, (int)x, 0x111, 0xF, 0xF, false); x = x < t ? x : t; // row_shr:1
  t = (unsigned)__builtin_amdgcn_update_dpp(-1, (int)x, 0x112, 0xF, 0xF, false); x = x < t ? x : t; // row_shr:2
  t = (unsigned)__builtin_amdgcn_update_dpp(-1, (int)x, 0x114, 0xF, 0xF, false); x = x < t ? x : t; // row_shr:4
  t = (unsigned)__builtin_amdgcn_update_dpp(-1, (int)x, 0x118, 0xF, 0xF, false); x = x < t ? x : t; // row_shr:8
  t = (unsigned)__builtin_amdgcn_update_dpp(-1, (int)x, 0x142, 0xF, 0xF, false); x = x < t ? x : t; // row_bcast:15
  t = (unsigned)__builtin_amdgcn_update_dpp(-1, (int)x, 0x143, 0xF, 0xF, false); x = x < t ? x : t; // row_bcast:31
  return x;
}

// ---------------------------------------------------------------------------
// Normalize mask to int32[B*N] in ws (bool vs int32 layout probe, see R0).
__global__ __launch_bounds__(256) void k_mask(const unsigned char* __restrict__ raw,
                                              int* __restrict__ mnorm){
  __shared__ int nonzero_probe;
  int tid = threadIdx.x;
  if (tid == 0) nonzero_probe = 0;
  __syncthreads();
  int local = 0;
  for (int i = tid; i < 4096; i += 256)
    local |= raw[4*i+1] | raw[4*i+2] | raw[4*i+3];
  if (local) atomicOr(&nonzero_probe, 1);
  __syncthreads();
  bool bool_layout = (nonzero_probe != 0);
  for (int i = tid; i < BB*NN; i += 256){
    int v = bool_layout ? (int)raw[i] : ((const int*)raw)[i];
    mnorm[i] = (v != 0) ? 1 : 0;
  }
}

// ---------------------------------------------------------------------------
// Per-row logsumexp over V=4096, masked rows only.
__global__ __launch_bounds__(256) void k_lse(const float* __restrict__ logits,
                                             const int* __restrict__ mask,
                                             float* __restrict__ lse){
  int row = blockIdx.x;
  if (mask[row] == 0) return;
  const float4* x = (const float4*)(logits + (size_t)row * VV);
  int tid = threadIdx.x;
  float4 a = x[tid], b = x[tid+256], c = x[tid+512], d = x[tid+768];
  float m = fmaxf(fmaxf(fmaxf(fmaxf(a.x,a.y),fmaxf(a.z,a.w)),
                        fmaxf(fmaxf(b.x,b.y),fmaxf(b.z,b.w))),
                  fmaxf(fmaxf(fmaxf(c.x,c.y),fmaxf(c.z,c.w)),
                        fmaxf(fmaxf(d.x,d.y),fmaxf(d.z,d.w))));
  __shared__ float red[8];
  float wm = wave_max(m);
  int wid = tid >> 6;
  if ((tid & 63) == 0) red[wid] = wm;
  __syncthreads();
  if (tid == 0) red[4] = fmaxf(fmaxf(red[0],red[1]), fmaxf(red[2],red[3]));
  __syncthreads();
  float M = red[4];
  float s = __expf(a.x-M)+__expf(a.y-M)+__expf(a.z-M)+__expf(a.w-M)
          + __expf(b.x-M)+__expf(b.y-M)+__expf(b.z-M)+__expf(b.w-M)
          + __expf(c.x-M)+__expf(c.y-M)+__expf(c.z-M)+__expf(c.w-M)
          + __expf(d.x-M)+__expf(d.y-M)+__expf(d.z-M)+__expf(d.w-M);
  float ws = wave_sum(s);
  __syncthreads();
  if ((tid & 63) == 0) red[wid] = ws;
  __syncthreads();
  if (tid == 0) lse[row] = M + __logf(red[0]+red[1]+red[2]+red[3]);
}

// ---------------------------------------------------------------------------
// Build (idx, gt) lists per (b, t) group via wave-ballot compaction.
__global__ __launch_bounds__(64) void k_group(const int* __restrict__ types,
                                              const int* __restrict__ mask,
                                              const int* __restrict__ gt,
                                              int* __restrict__ idxg,
                                              int* __restrict__ gtkg,
                                              int* __restrict__ kcnt){
  int g = blockIdx.x;
  int b = g >> 3, t = g & 7;
  int lane = threadIdx.x;
  int base = 0;
  for (int r = 0; r < NN/64; r++){
    int pos = r*64 + lane;
    int o = b*NN + pos;
    bool pred = (types[o] == t) && (mask[o] != 0);
    unsigned long long bal = __ballot(pred);
    int pre = __popcll(bal & ((1ull << lane) - 1ull));
    int dst = base + pre;
    if (pred && dst < KMAX){
      idxg[g*KMAX + dst] = pos;
      gtkg[g*KMAX + dst] = gt[o];
    }
    base += __popcll(bal);
  }
  if (lane == 0) kcnt[g] = (base > KMAX) ? KMAX : base;
}

// ---------------------------------------------------------------------------
// JV LAP, accumulated-delta (lapjv/Dijkstra) formulation of the e-maxx
// reference. One wave per group, lane owns cols {lane+1, lane+65}.
// Inner loop: DPP VALU argmin + 3 parallel bpermutes + one LDS row read.
// No barriers or cross-lane LDS writes inside the scan; duals updated once
// per row (exactly equivalent to the reference's per-step delta updates).
__global__ __launch_bounds__(64) void k_jv(const float* __restrict__ logits,
                                           const int* __restrict__ idxg,
                                           const int* __restrict__ gtkg,
                                           const int* __restrict__ kcnt,
                                           float* __restrict__ gval){
  __shared__ float Cm[KMAX*STRIDE];    // 61504 B
  __shared__ float u_l[KMAX+1];        // row potentials (rows 1..k); u_l[0] scratch
  __shared__ int   p_l[KMAX+1];        // col -> row (1-based; 0 = unassigned)
  __shared__ int   way_l[KMAX+1];      // predecessor column for augment walk
  int g = blockIdx.x;
  int b = g >> 3;
  int lane = threadIdx.x;
  int k = kcnt[g];
  if (k > KMAX) k = KMAX;
  if (k == 0){ if (lane == 0) gval[g] = 0.f; return; }

  int col0 = lane + 1, col1 = lane + 65;
  bool a0 = (col0 <= k), a1 = (col1 <= k);
  int gc0 = a0 ? gtkg[g*KMAX + lane]      : 0;
  int gc1 = a1 ? gtkg[g*KMAX + lane + 64] : 0;
  for (int i = 0; i < k; i++){
    const float* rowp = logits + ((size_t)(b*NN + idxg[g*KMAX + i])) * VV;
    if (a0) Cm[i*STRIDE + lane]      = -rowp[gc0];
    if (a1) Cm[i*STRIDE + lane + 64] = -rowp[gc1];
  }
  if (a0){ u_l[col0] = 0.f; p_l[col0] = 0; }
  if (a1){ u_l[col1] = 0.f; p_l[col1] = 0; }
  if (lane == 0){ u_l[0] = 0.f; p_l[0] = 0; }
  float v0 = 0.f, v1 = 0.f;          // column potentials (register)
  int   rp0 = 0, rp1 = 0;            // cached p[col] (valid during a scan)
  float rpu0 = 0.f, rpu1 = 0.f;      // cached u[p[col]]
  __syncthreads();

  for (int i = 1; i <= k; i++){
    // dist init: dist[j] = C[i][j] - u[i](=0) - v[j]
    float dist0 = a0 ? (Cm[(i-1)*STRIDE + lane]      - v0) : INFINITY;
    float dist1 = a1 ? (Cm[(i-1)*STRIDE + lane + 64] - v1) : INFINITY;
    int way0 = 0, way1 = 0;
    bool used0 = false, used1 = false;
    int j_end; float delta_end;

    while (true){
      // packed argmin key: truncated sortable float | (col-1); ties -> lower col
      unsigned q0 = (a0 && !used0) ? ((fkey(dist0) & 0xFFFFFF80u) | (unsigned)(col0-1)) : 0xFFFFFFFFu;
      unsigned q1 = (a1 && !used1) ? ((fkey(dist1) & 0xFFFFFF80u) | (unsigned)(col1-1)) : 0xFFFFFFFFu;
      unsigned key = q0 < q1 ? q0 : q1;
      key = dpp_min64(key);
      unsigned kmin = (unsigned)__builtin_amdgcn_readlane((int)key, 63);
      int j1 = (int)(kmin & 127u) + 1;
      int owner = (j1-1) & 63, slot = (j1-1) >> 6;
      int addr = owner << 2;
      float dsel  = slot ? dist1 : dist0;
      int   psel  = slot ? rp1   : rp0;
      float pusel = slot ? rpu1  : rpu0;
      int di  = __builtin_amdgcn_ds_bpermute(addr, __float_as_int(dsel));
      int pi  = __builtin_amdgcn_ds_bpermute(addr, psel);
      int pui = __builtin_amdgcn_ds_bpermute(addr, __float_as_int(pusel));
      float delta = __int_as_float(di);
      int i0 = __builtin_amdgcn_readfirstlane(pi);
      used0 |= (j1 == col0);
      used1 |= (j1 == col1);
      if (i0 == 0){ j_end = j1; delta_end = delta; break; }
      // relax with row i0: nd = delta + C[i0][j] - u[i0] - v[j]
      float base = delta - __int_as_float(pui);
      int off = (i0 - 1) * STRIDE;
      float c0 = Cm[off + lane];
      float c1 = Cm[off + 64 + lane];
      float nd0 = base + c0 - v0;
      float nd1 = base + c1 - v1;
      if (a0 && !used0 && (nd0 < dist0)){ dist0 = nd0; way0 = j1; }
      if (a1 && !used1 && (nd1 < dist1)){ dist1 = nd1; way1 = j1; }
    }

    // dual updates (once per row; j_end's adj is exactly 0 -> harmless)
    if (used0){ float adj = delta_end - dist0; v0 -= adj; u_l[rp0] = rpu0 + adj; }
    if (used1){ float adj = delta_end - dist1; v1 -= adj; u_l[rp1] = rpu1 + adj; }
    if (lane == 0) u_l[i] = delta_end;   // u[i] was 0 before its own scan
    if (a0) way_l[col0] = way0;
    if (a1) way_l[col1] = way1;
    __syncthreads();

    // augment: walk predecessor chain (wave-uniform; lane 0 commits p)
    int j0 = j_end;
    while (true){
      int jw = way_l[j0];
      int pr = p_l[jw];                // p_l[0] exists; value unused when jw==0
      int pw = (jw == 0) ? i : pr;
      if (lane == 0) p_l[j0] = pw;
      if (jw == 0) break;
      j0 = jw;
    }
    __syncthreads();

    // refresh register caches for next scan
    rp0 = a0 ? p_l[col0] : 0;
    rp1 = a1 ? p_l[col1] : 0;
    rpu0 = (a0 && rp0 > 0) ? u_l[rp0] : 0.f;
    rpu1 = (a1 && rp1 > 0) ? u_l[rp1] : 0.f;
  }

  __syncthreads();
  float acc = 0.f;
  if (a0) acc += Cm[(p_l[col0]-1)*STRIDE + lane];
  if (a1) acc += Cm[(p_l[col1]-1)*STRIDE + lane + 64];
  acc = wave_sum(acc);
  if (lane == 0) gval[g] = -acc;       // max-assignment value of A
}

// ---------------------------------------------------------------------------
// loss = (sum_masked lse - sum_g gval) / total_masked
__global__ __launch_bounds__(256) void k_final(const float* __restrict__ lse,
                                               const int* __restrict__ mask,
                                               const float* __restrict__ gval,
                                               float* __restrict__ out){
  __shared__ double sd[256];
  __shared__ double sg[256];
  __shared__ int    si[256];
  int tid = threadIdx.x;
  double s = 0.0, gs = 0.0; int c = 0;
  for (int i = tid; i < BB*NN; i += 256)
    if (mask[i]){ s += (double)lse[i]; c++; }
  for (int i = tid; i < NG; i += 256) gs += (double)gval[i];
  sd[tid] = s; sg[tid] = gs; si[tid] = c;
  __syncthreads();
  for (int off = 128; off; off >>= 1){
    if (tid < off){ sd[tid] += sd[tid+off]; sg[tid] += sg[tid+off]; si[tid] += si[tid+off]; }
    __syncthreads();
  }
  if (tid == 0) out[0] = (float)((sd[0] - sg[0]) / (double)si[0]);
}

extern "C" void kernel_launch(void* const* d_in, const int* in_sizes, int n_in,
                              void* d_out, int out_size, void* d_ws, size_t ws_size,
                              hipStream_t stream) {
  const float* logits = (const float*)d_in[0];
  const int*   gt     = (const int*)d_in[1];
  const int*   types  = (const int*)d_in[2];
  const unsigned char* maskraw = (const unsigned char*)d_in[3];
  float* out = (float*)d_out;

  char* w = (char*)d_ws;
  float* lse   = (float*)w;  w += (size_t)BB*NN*4;
  int*   mnorm = (int*)w;    w += (size_t)BB*NN*4;
  int*   idxg  = (int*)w;    w += (size_t)NG*KMAX*4;
  int*   gtkg  = (int*)w;    w += (size_t)NG*KMAX*4;
  int*   kcnt  = (int*)w;    w += 1024;
  float* gval  = (float*)w;  w += 1024;

  k_mask <<<1,      256, 0, stream>>>(maskraw, mnorm);
  k_lse  <<<BB*NN,  256, 0, stream>>>(logits, mnorm, lse);
  k_group<<<NG,      64, 0, stream>>>(types, mnorm, gt, idxg, gtkg, kcnt);
  k_jv   <<<NG,      64, 0, stream>>>(logits, idxg, gtkg, kcnt, gval);
  k_final<<<1,      256, 0, stream>>>(lse, mnorm, gval, out);
}

// Round 3
// 500.127 us; speedup vs baseline: 1.7821x; 1.2879x over previous
//
#include <hip/hip_runtime.h>
#include <math.h>

#define BB 16
#define NN 1024
#define VV 4096
#define TT 8
#define NG (BB*TT)   // 128 groups
#define KMAX 124     // max group size; Binomial(1024,1/16): mean 64, sigma 7.75 -> ~8 sigma
#define STRIDE 124

__device__ __forceinline__ float wave_max(float v){
  #pragma unroll
  for (int off = 32; off; off >>= 1) v = fmaxf(v, __shfl_down(v, off));
  return v;
}
__device__ __forceinline__ float wave_sum(float v){
  #pragma unroll
  for (int off = 32; off; off >>= 1) v += __shfl_down(v, off);
  return v;
}

// monotone float <-> uint key (finite values)
__device__ __forceinline__ unsigned fkey(float f){
  unsigned b = __float_as_uint(f);
  return b ^ ((unsigned)((int)b >> 31) | 0x80000000u);
}
__device__ __forceinline__ float inv_fkey(unsigned u){
  unsigned b = (u & 0x80000000u) ? (u ^ 0x80000000u) : ~u;
  return __uint_as_float(b);
}

// 64-lane min-reduction via DPP (VALU-only). Result valid in lane 63.
__device__ __forceinline__ unsigned dpp_min64(unsigned x){
  unsigned t;
  t = (unsigned)__builtin_amdgcn_update_dpp(-1, (int)x, 0x111, 0xF, 0xF, false); x = x < t ? x : t;
  t = (unsigned)__builtin_amdgcn_update_dpp(-1, (int)x, 0x112, 0xF, 0xF, false); x = x < t ? x : t;
  t = (unsigned)__builtin_amdgcn_update_dpp(-1, (int)x, 0x114, 0xF, 0xF, false); x = x < t ? x : t;
  t = (unsigned)__builtin_amdgcn_update_dpp(-1, (int)x, 0x118, 0xF, 0xF, false); x = x < t ? x : t;
  t = (unsigned)__builtin_amdgcn_update_dpp(-1, (int)x, 0x142, 0xF, 0xF, false); x = x < t ? x : t;
  t = (unsigned)__builtin_amdgcn_update_dpp(-1, (int)x, 0x143, 0xF, 0xF, false); x = x < t ? x : t;
  return x;
}

// ---------------------------------------------------------------------------
// Fused mask-normalize + per-(b,t) group build. Each block probes the mask
// layout itself (bool 1B vs int32 4B; bytes 4i+1..3 all-zero => int32).
__global__ __launch_bounds__(64) void k_prep(const unsigned char* __restrict__ raw,
                                             const int* __restrict__ types,
                                             const int* __restrict__ gt,
                                             int* __restrict__ mnorm,
                                             int* __restrict__ idxg,
                                             int* __restrict__ gtkg,
                                             int* __restrict__ kcnt){
  int g = blockIdx.x, b = g >> 3, t = g & 7, lane = threadIdx.x;
  int local = 0;
  for (int i = lane; i < 4096; i += 64)
    local |= raw[4*i+1] | raw[4*i+2] | raw[4*i+3];
  bool bool_layout = (__ballot(local != 0) != 0ull);
  const int* rawi = (const int*)raw;
  // mnorm chunk: rows [g*128, g*128+128)
  for (int r = 0; r < 2; r++){
    int o = g*128 + r*64 + lane;
    int v = bool_layout ? (int)raw[o] : rawi[o];
    mnorm[o] = (v != 0);
  }
  int base = 0;
  for (int r = 0; r < NN/64; r++){
    int pos = r*64 + lane, o = b*NN + pos;
    int mv = bool_layout ? (int)raw[o] : rawi[o];
    bool pred = (types[o] == t) && (mv != 0);
    unsigned long long ball = __ballot(pred);
    int dst = base + __popcll(ball & ((1ull << lane) - 1ull));
    if (pred && dst < KMAX){
      idxg[g*KMAX + dst] = pos;
      gtkg[g*KMAX + dst] = gt[o];
    }
    base += __popcll(ball);
  }
  if (lane == 0) kcnt[g] = (base > KMAX) ? KMAX : base;
}

// ---------------------------------------------------------------------------
// Per-row logsumexp over V=4096, masked rows only.
__global__ __launch_bounds__(256) void k_lse(const float* __restrict__ logits,
                                             const int* __restrict__ mask,
                                             float* __restrict__ lse){
  int row = blockIdx.x;
  if (mask[row] == 0) return;
  const float4* x = (const float4*)(logits + (size_t)row * VV);
  int tid = threadIdx.x;
  float4 a = x[tid], b = x[tid+256], c = x[tid+512], d = x[tid+768];
  float m = fmaxf(fmaxf(fmaxf(fmaxf(a.x,a.y),fmaxf(a.z,a.w)),
                        fmaxf(fmaxf(b.x,b.y),fmaxf(b.z,b.w))),
                  fmaxf(fmaxf(fmaxf(c.x,c.y),fmaxf(c.z,c.w)),
                        fmaxf(fmaxf(d.x,d.y),fmaxf(d.z,d.w))));
  __shared__ float red[8];
  float wm = wave_max(m);
  int wid = tid >> 6;
  if ((tid & 63) == 0) red[wid] = wm;
  __syncthreads();
  if (tid == 0) red[4] = fmaxf(fmaxf(red[0],red[1]), fmaxf(red[2],red[3]));
  __syncthreads();
  float M = red[4];
  float s = __expf(a.x-M)+__expf(a.y-M)+__expf(a.z-M)+__expf(a.w-M)
          + __expf(b.x-M)+__expf(b.y-M)+__expf(b.z-M)+__expf(b.w-M)
          + __expf(c.x-M)+__expf(c.y-M)+__expf(c.z-M)+__expf(c.w-M)
          + __expf(d.x-M)+__expf(d.y-M)+__expf(d.z-M)+__expf(d.w-M);
  float ws = wave_sum(s);
  __syncthreads();
  if ((tid & 63) == 0) red[wid] = ws;
  __syncthreads();
  if (tid == 0) lse[row] = M + __logf(red[0]+red[1]+red[2]+red[3]);
}

// ---------------------------------------------------------------------------
// LAP per group: lapjv-style init (column reduction + 2x augmenting row
// reduction) + Dijkstra shortest-augmenting-path for the few remaining free
// rows. One wave per group; lane owns cols {lane+1, lane+65} (1-based).
// All phases maintain dual feasibility (rc >= 0, tight on assigned arcs),
// so the result is the exact optimal assignment value.
__global__ __launch_bounds__(64) void k_jv(const float* __restrict__ logits,
                                           const int* __restrict__ idxg,
                                           const int* __restrict__ gtkg,
                                           const int* __restrict__ kcnt,
                                           float* __restrict__ gval){
  __shared__ float Cm[KMAX*STRIDE];    // 61504 B
  __shared__ float u_l[KMAX+1];        // row potentials (rows 1..k); [0] scratch
  __shared__ int   p_l[KMAX+1];        // col -> row (1-based; 0 = free)
  __shared__ int   way_l[KMAX+1];      // scan predecessors; reused as idx stage
  __shared__ int   rowown[KMAX];       // CR: row -> winning col (-1 free)
  __shared__ int   listA[KMAX];
  __shared__ int   listB[KMAX];
  int g = blockIdx.x, b = g >> 3, lane = threadIdx.x;
  int k = kcnt[g];
  if (k > KMAX) k = KMAX;
  if (k == 0){ if (lane == 0) gval[g] = 0.f; return; }

  int col0 = lane + 1, col1 = lane + 65;
  bool a0 = (col0 <= k), a1 = (col1 <= k);
  int gc0 = a0 ? gtkg[g*KMAX + lane]      : 0;
  int gc1 = a1 ? gtkg[g*KMAX + lane + 64] : 0;

  // stage row indices into way_l (reused later by scans)
  if (lane < k)      way_l[lane]    = idxg[g*KMAX + lane];
  if (lane+64 < k)   way_l[lane+64] = idxg[g*KMAX + lane + 64];
  u_l[col0] = 0.f; p_l[col0] = 0;
  if (col1 <= KMAX){ u_l[col1] = 0.f; p_l[col1] = 0; }
  if (lane == 0){ u_l[0] = 0.f; p_l[0] = 0; }
  rowown[lane] = -1;
  if (lane + 64 < KMAX) rowown[lane+64] = -1;
  __syncthreads();

  // ---- staging: 4-row software pipeline (8 gathers in flight) ----
  const size_t rowbase = (size_t)b * NN;
  for (int i = 0; i < k; i += 4){
    int r0 = i, r1 = min(i+1, k-1), r2 = min(i+2, k-1), r3 = min(i+3, k-1);
    const float* q0 = logits + (rowbase + way_l[r0]) * VV;
    const float* q1 = logits + (rowbase + way_l[r1]) * VV;
    const float* q2 = logits + (rowbase + way_l[r2]) * VV;
    const float* q3 = logits + (rowbase + way_l[r3]) * VV;
    float x00 = q0[gc0], x01 = q0[gc1];
    float x10 = q1[gc0], x11 = q1[gc1];
    float x20 = q2[gc0], x21 = q2[gc1];
    float x30 = q3[gc0], x31 = q3[gc1];
    Cm[r0*STRIDE + lane] = -x00; Cm[r0*STRIDE + 64 + lane] = -x01;
    Cm[r1*STRIDE + lane] = -x10; Cm[r1*STRIDE + 64 + lane] = -x11;
    Cm[r2*STRIDE + lane] = -x20; Cm[r2*STRIDE + 64 + lane] = -x21;
    Cm[r3*STRIDE + lane] = -x30; Cm[r3*STRIDE + 64 + lane] = -x31;
  }
  __syncthreads();

  // ---- column reduction: v[j] = min_i C[i][j]; assign argmin row if free ----
  float v0 = 0.f, v1 = 0.f;
  int ra0 = -1, ra1 = -1;
  if (a0){ float m = INFINITY; int rm = 0;
    for (int i = 0; i < k; i++){ float c = Cm[i*STRIDE + lane]; if (c < m){ m = c; rm = i; } }
    v0 = m; ra0 = rm; }
  if (a1){ float m = INFINITY; int rm = 0;
    for (int i = 0; i < k; i++){ float c = Cm[i*STRIDE + 64 + lane]; if (c < m){ m = c; rm = i; } }
    v1 = m; ra1 = rm; }
  if (a0){ if (atomicCAS(&rowown[ra0], -1, col0) == -1) p_l[col0] = ra0 + 1; }
  if (a1){ if (atomicCAS(&rowown[ra1], -1, col1) == -1) p_l[col1] = ra1 + 1; }
  __syncthreads();

  // free-row list
  bool f0 = (lane < k)    && (rowown[lane]    == -1);
  bool f1 = (lane+64 < k) && (rowown[lane+64] == -1);
  unsigned long long B0 = __ballot(f0), B1 = __ballot(f1);
  unsigned long long lm = (1ull << lane) - 1ull;
  int n0 = __popcll(B0);
  if (f0) listA[__popcll(B0 & lm)]      = lane + 1;   // rows 1-based
  if (f1) listA[n0 + __popcll(B1 & lm)] = lane + 65;
  int nCur = n0 + __popcll(B1);
  __syncthreads();

  // ---- augmenting row reduction, 2 passes ----
  int* curL = listA; int* nxtL = listB;
  for (int pass = 0; pass < 2; pass++){
    int nNxt = 0;
    for (int fr = 0; fr < nCur; fr++){
      int row = curL[fr];                       // wave-uniform
      int off = (row - 1) * STRIDE;
      float rc0 = a0 ? (Cm[off + lane]      - v0) : INFINITY;
      float rc1 = a1 ? (Cm[off + 64 + lane] - v1) : INFINITY;
      unsigned k0 = fkey(rc0), k1 = fkey(rc1);
      unsigned kk = k0 < k1 ? k0 : k1;
      unsigned m1 = (unsigned)__builtin_amdgcn_readlane((int)dpp_min64(kk), 63);
      int cand = (k0 == m1) ? col0 : ((k1 == m1) ? col1 : 0);
      unsigned long long bl1 = __ballot(cand != 0);
      int ow1 = __ffsll(bl1) - 1;
      int j1 = __builtin_amdgcn_readlane(cand, ow1);
      float u1 = inv_fkey(m1);
      unsigned k0b = (col0 == j1) ? 0xFFFFFFFFu : k0;
      unsigned k1b = (col1 == j1) ? 0xFFFFFFFFu : k1;
      unsigned kkb = k0b < k1b ? k0b : k1b;
      unsigned m2 = (unsigned)__builtin_amdgcn_readlane((int)dpp_min64(kkb), 63);
      float u2 = inv_fkey(m2);
      int jt = j1;
      if (u1 < u2){
        if (col0 == j1) v0 -= (u2 - u1);
        if (col1 == j1) v1 -= (u2 - u1);
      } else {
        int own1 = p_l[j1];
        if (own1 != 0){
          int cand2 = (k0b == m2) ? col0 : ((k1b == m2) ? col1 : 0);
          unsigned long long bl2 = __ballot(cand2 != 0);
          int ow2 = __ffsll(bl2) - 1;
          jt = __builtin_amdgcn_readlane(cand2, ow2);
        }
      }
      int iprev = p_l[jt];                      // wave-uniform
      if (lane == 0){ p_l[jt] = row; u_l[row] = u2; }
      if (iprev != 0){ if (lane == 0) nxtL[nNxt] = iprev; nNxt++; }
      __syncthreads();
    }
    int* tmp = curL; curL = nxtL; nxtL = tmp;
    nCur = nNxt;
  }

  // ---- Dijkstra shortest augmenting path for remaining free rows ----
  for (int fr = 0; fr < nCur; fr++){
    int irow = curL[fr];
    int rp0 = a0 ? p_l[col0] : 0;
    int rp1 = a1 ? p_l[col1] : 0;
    float rpu0 = (rp0 > 0) ? u_l[rp0] : 0.f;
    float rpu1 = (rp1 > 0) ? u_l[rp1] : 0.f;
    int off = (irow - 1) * STRIDE;
    float dist0 = a0 ? (Cm[off + lane]      - v0) : INFINITY;
    float dist1 = a1 ? (Cm[off + 64 + lane] - v1) : INFINITY;
    int way0 = 0, way1 = 0;
    bool used0 = false, used1 = false;
    int j_end; float delta_end;
    while (true){
      unsigned q0 = (a0 && !used0) ? ((fkey(dist0) & 0xFFFFFF80u) | (unsigned)(col0-1)) : 0xFFFFFFFFu;
      unsigned q1 = (a1 && !used1) ? ((fkey(dist1) & 0xFFFFFF80u) | (unsigned)(col1-1)) : 0xFFFFFFFFu;
      unsigned key = q0 < q1 ? q0 : q1;
      unsigned kmin = (unsigned)__builtin_amdgcn_readlane((int)dpp_min64(key), 63);
      int j1 = (int)(kmin & 127u) + 1;
      int owner = (j1-1) & 63, slot = (j1-1) >> 6, addr = owner << 2;
      float dsel  = slot ? dist1 : dist0;
      int   psel  = slot ? rp1   : rp0;
      float pusel = slot ? rpu1  : rpu0;
      int di  = __builtin_amdgcn_ds_bpermute(addr, __float_as_int(dsel));
      int pi  = __builtin_amdgcn_ds_bpermute(addr, psel);
      int pui = __builtin_amdgcn_ds_bpermute(addr, __float_as_int(pusel));
      float delta = __int_as_float(di);
      int i0 = __builtin_amdgcn_readfirstlane(pi);
      used0 |= (j1 == col0);
      used1 |= (j1 == col1);
      if (i0 == 0){ j_end = j1; delta_end = delta; break; }
      float base = delta - __int_as_float(pui);
      int o2 = (i0 - 1) * STRIDE;
      float c0 = Cm[o2 + lane];
      float c1 = Cm[o2 + 64 + lane];
      float nd0 = base + c0 - v0;
      float nd1 = base + c1 - v1;
      if (a0 && !used0 && (nd0 < dist0)){ dist0 = nd0; way0 = j1; }
      if (a1 && !used1 && (nd1 < dist1)){ dist1 = nd1; way1 = j1; }
    }
    if (used0){ float adj = delta_end - dist0; v0 -= adj; u_l[rp0] = rpu0 + adj; }
    if (used1){ float adj = delta_end - dist1; v1 -= adj; u_l[rp1] = rpu1 + adj; }
    if (lane == 0) u_l[irow] = delta_end;
    if (a0) way_l[col0] = way0;
    if (a1) way_l[col1] = way1;
    __syncthreads();
    int j0 = j_end;
    while (true){
      int jw = way_l[j0];
      int pr = p_l[jw];
      int pw = (jw == 0) ? irow : pr;
      if (lane == 0) p_l[j0] = pw;
      if (jw == 0) break;
      j0 = jw;
    }
    __syncthreads();
  }

  __syncthreads();
  float acc = 0.f;
  if (a0) acc += Cm[(p_l[col0]-1)*STRIDE + lane];
  if (a1) acc += Cm[(p_l[col1]-1)*STRIDE + 64 + lane];
  acc = wave_sum(acc);
  if (lane == 0) gval[g] = -acc;       // max-assignment value of A
}

// ---------------------------------------------------------------------------
// loss = (sum_masked lse - sum_g gval) / total_masked
__global__ __launch_bounds__(256) void k_final(const float* __restrict__ lse,
                                               const int* __restrict__ mask,
                                               const float* __restrict__ gval,
                                               float* __restrict__ out){
  __shared__ double sd[256];
  __shared__ double sg[256];
  __shared__ int    si[256];
  int tid = threadIdx.x;
  double s = 0.0, gs = 0.0; int c = 0;
  for (int i = tid; i < BB*NN; i += 256)
    if (mask[i]){ s += (double)lse[i]; c++; }
  for (int i = tid; i < NG; i += 256) gs += (double)gval[i];
  sd[tid] = s; sg[tid] = gs; si[tid] = c;
  __syncthreads();
  for (int off = 128; off; off >>= 1){
    if (tid < off){ sd[tid] += sd[tid+off]; sg[tid] += sg[tid+off]; si[tid] += si[tid+off]; }
    __syncthreads();
  }
  if (tid == 0) out[0] = (float)((sd[0] - sg[0]) / (double)si[0]);
}

extern "C" void kernel_launch(void* const* d_in, const int* in_sizes, int n_in,
                              void* d_out, int out_size, void* d_ws, size_t ws_size,
                              hipStream_t stream) {
  const float* logits = (const float*)d_in[0];
  const int*   gt     = (const int*)d_in[1];
  const int*   types  = (const int*)d_in[2];
  const unsigned char* maskraw = (const unsigned char*)d_in[3];
  float* out = (float*)d_out;

  char* w = (char*)d_ws;
  float* lse   = (float*)w;  w += (size_t)BB*NN*4;
  int*   mnorm = (int*)w;    w += (size_t)BB*NN*4;
  int*   idxg  = (int*)w;    w += (size_t)NG*KMAX*4;
  int*   gtkg  = (int*)w;    w += (size_t)NG*KMAX*4;
  int*   kcnt  = (int*)w;    w += 1024;
  float* gval  = (float*)w;  w += 1024;

  k_prep <<<NG,     64, 0, stream>>>(maskraw, types, gt, mnorm, idxg, gtkg, kcnt);
  k_lse  <<<BB*NN, 256, 0, stream>>>(logits, mnorm, lse);
  k_jv   <<<NG,     64, 0, stream>>>(logits, idxg, gtkg, kcnt, gval);
  k_final<<<1,     256, 0, stream>>>(lse, mnorm, gval, out);
}

// Round 4
// 457.577 us; speedup vs baseline: 1.9478x; 1.0930x over previous
//
#include <hip/hip_runtime.h>
#include <math.h>

#define BB 16
#define NN 1024
#define VV 4096
#define TT 8
#define NG (BB*TT)   // 128 groups
#define KMAX 124     // max group size; Binomial(1024,1/16): mean 64, sigma 7.75 -> ~8 sigma
#define STRIDE 124

__device__ __forceinline__ float wave_max(float v){
  #pragma unroll
  for (int off = 32; off; off >>= 1) v = fmaxf(v, __shfl_down(v, off));
  return v;
}
__device__ __forceinline__ float wave_sum(float v){
  #pragma unroll
  for (int off = 32; off; off >>= 1) v += __shfl_down(v, off);
  return v;
}

// monotone float <-> uint key (finite values)
__device__ __forceinline__ unsigned fkey(float f){
  unsigned b = __float_as_uint(f);
  return b ^ ((unsigned)((int)b >> 31) | 0x80000000u);
}
__device__ __forceinline__ float inv_fkey(unsigned u){
  unsigned b = (u & 0x80000000u) ? (u ^ 0x80000000u) : ~u;
  return __uint_as_float(b);
}

// 64-lane min-reduction via DPP (VALU-only). Result valid in lane 63.
__device__ __forceinline__ unsigned dpp_min64(unsigned x){
  unsigned t;
  t = (unsigned)__builtin_amdgcn_update_dpp(-1, (int)x, 0x111, 0xF, 0xF, false); x = x < t ? x : t;
  t = (unsigned)__builtin_amdgcn_update_dpp(-1, (int)x, 0x112, 0xF, 0xF, false); x = x < t ? x : t;
  t = (unsigned)__builtin_amdgcn_update_dpp(-1, (int)x, 0x114, 0xF, 0xF, false); x = x < t ? x : t;
  t = (unsigned)__builtin_amdgcn_update_dpp(-1, (int)x, 0x118, 0xF, 0xF, false); x = x < t ? x : t;
  t = (unsigned)__builtin_amdgcn_update_dpp(-1, (int)x, 0x142, 0xF, 0xF, false); x = x < t ? x : t;
  t = (unsigned)__builtin_amdgcn_update_dpp(-1, (int)x, 0x143, 0xF, 0xF, false); x = x < t ? x : t;
  return x;
}

// ---------------------------------------------------------------------------
// Per-row logsumexp over V=4096. Self-contained: probes mask layout (bool 1B
// vs int32 4B: bytes 4i+1..3 all-zero over 256 probes => int32; else bool).
// Writes lse[row]=0 for unmasked rows (d_ws is poisoned 0xAA by the harness).
__global__ __launch_bounds__(256) void k_lse(const float* __restrict__ logits,
                                             const unsigned char* __restrict__ raw,
                                             float* __restrict__ lse){
  int row = blockIdx.x;
  int tid = threadIdx.x;
  __shared__ int probe_nz;
  if (tid == 0) probe_nz = 0;
  __syncthreads();
  uchar4 pv = ((const uchar4*)raw)[tid];          // elements 0..255 of int32 view
  if (pv.y | pv.z | pv.w) atomicOr(&probe_nz, 1);
  __syncthreads();
  bool bool_layout = (probe_nz != 0);
  int mv = bool_layout ? (int)raw[row] : ((const int*)raw)[row];
  if (mv == 0){ if (tid == 0) lse[row] = 0.f; return; }

  const float4* x = (const float4*)(logits + (size_t)row * VV);
  float4 a = x[tid], b = x[tid+256], c = x[tid+512], d = x[tid+768];
  float m = fmaxf(fmaxf(fmaxf(fmaxf(a.x,a.y),fmaxf(a.z,a.w)),
                        fmaxf(fmaxf(b.x,b.y),fmaxf(b.z,b.w))),
                  fmaxf(fmaxf(fmaxf(c.x,c.y),fmaxf(c.z,c.w)),
                        fmaxf(fmaxf(d.x,d.y),fmaxf(d.z,d.w))));
  __shared__ float red[8];
  float wm = wave_max(m);
  int wid = tid >> 6;
  if ((tid & 63) == 0) red[wid] = wm;
  __syncthreads();
  if (tid == 0) red[4] = fmaxf(fmaxf(red[0],red[1]), fmaxf(red[2],red[3]));
  __syncthreads();
  float M = red[4];
  float s = __expf(a.x-M)+__expf(a.y-M)+__expf(a.z-M)+__expf(a.w-M)
          + __expf(b.x-M)+__expf(b.y-M)+__expf(b.z-M)+__expf(b.w-M)
          + __expf(c.x-M)+__expf(c.y-M)+__expf(c.z-M)+__expf(c.w-M)
          + __expf(d.x-M)+__expf(d.y-M)+__expf(d.z-M)+__expf(d.w-M);
  float ws = wave_sum(s);
  __syncthreads();
  if ((tid & 63) == 0) red[wid] = ws;
  __syncthreads();
  if (tid == 0) lse[row] = M + __logf(red[0]+red[1]+red[2]+red[3]);
}

// ---------------------------------------------------------------------------
// LAP per group with fused group-build. lapjv init (column reduction + 3x
// augmenting row reduction) + Dijkstra SAP for remaining free rows.
// One wave per block; lane owns cols {lane+1, lane+65} (1-based).
// All phases maintain dual feasibility => exact optimal value.
__global__ __launch_bounds__(64) void k_jv(const float* __restrict__ logits,
                                           const int* __restrict__ types,
                                           const int* __restrict__ gt,
                                           const unsigned char* __restrict__ raw,
                                           int* __restrict__ kcnt,
                                           float* __restrict__ gval){
  __shared__ float Cm[KMAX*STRIDE];    // 61504 B
  __shared__ float u_l[KMAX+1];        // row potentials (rows 1..k); [0] scratch
  __shared__ int   p_l[KMAX+1];        // col -> row (1-based; 0 = free)
  __shared__ int   way_l[KMAX+1];      // idx staging, then scan predecessors
  __shared__ int   rowown[KMAX];       // CR: row -> winning col (-1 free)
  __shared__ int   listA[KMAX];        // gtk staging, then free-row list
  __shared__ int   listB[KMAX];
  int g = blockIdx.x, b = g >> 3, t = g & 7, lane = threadIdx.x;
  unsigned long long lm = (1ull << lane) - 1ull;

  // ---- inline prep: mask layout probe + ballot compaction ----
  int local = 0;
  const uchar4* r4 = (const uchar4*)raw;
  #pragma unroll
  for (int r = 0; r < 4; r++){ uchar4 u = r4[lane + 64*r]; local |= (u.y | u.z | u.w); }
  bool bool_layout = (__ballot(local != 0) != 0ull);
  const int* rawi = (const int*)raw;
  int base = 0;
  for (int r = 0; r < NN/64; r++){
    int pos = r*64 + lane, o = b*NN + pos;
    int mv = bool_layout ? (int)raw[o] : rawi[o];
    bool pred = (types[o] == t) && (mv != 0);
    unsigned long long ball = __ballot(pred);
    int dst = base + __popcll(ball & lm);
    if (pred && dst < KMAX){ way_l[dst] = pos; listA[dst] = gt[o]; }
    base += __popcll(ball);
  }
  int k = (base > KMAX) ? KMAX : base;
  if (lane == 0) kcnt[g] = k;
  if (k == 0){ if (lane == 0) gval[g] = 0.f; return; }

  int col0 = lane + 1, col1 = lane + 65;
  bool a0 = (col0 <= k), a1 = (col1 <= k);
  int gc0 = a0 ? listA[lane]      : 0;   // same-wave LDS: in-order DS pipe
  int gc1 = a1 ? listA[lane + 64] : 0;

  u_l[col0] = 0.f; p_l[col0] = 0;
  if (col1 <= KMAX){ u_l[col1] = 0.f; p_l[col1] = 0; }
  if (lane == 0){ u_l[0] = 0.f; p_l[0] = 0; }
  rowown[lane] = -1;
  if (lane + 64 < KMAX) rowown[lane+64] = -1;
  __syncthreads();

  // ---- staging: 8-row software pipeline (16 gathers in flight; L3-hot) ----
  const size_t rowbase = (size_t)b * NN;
  for (int i = 0; i < k; i += 8){
    float xs0[8], xs1[8]; int rr[8];
    #pragma unroll
    for (int s = 0; s < 8; s++){
      int r = i + s; r = (r < k) ? r : (k - 1); rr[s] = r;
      const float* q = logits + (rowbase + way_l[r]) * VV;
      xs0[s] = q[gc0]; xs1[s] = q[gc1];
    }
    #pragma unroll
    for (int s = 0; s < 8; s++){
      Cm[rr[s]*STRIDE + lane]      = -xs0[s];
      Cm[rr[s]*STRIDE + 64 + lane] = -xs1[s];
    }
  }
  __syncthreads();

  // ---- column reduction: v[j] = min_i C[i][j]; assign argmin row if free ----
  float v0 = 0.f, v1 = 0.f;
  int ra0 = -1, ra1 = -1;
  if (a0){ float m = INFINITY; int rm = 0;
    for (int i = 0; i < k; i++){ float c = Cm[i*STRIDE + lane]; if (c < m){ m = c; rm = i; } }
    v0 = m; ra0 = rm; }
  if (a1){ float m = INFINITY; int rm = 0;
    for (int i = 0; i < k; i++){ float c = Cm[i*STRIDE + 64 + lane]; if (c < m){ m = c; rm = i; } }
    v1 = m; ra1 = rm; }
  if (a0){ if (atomicCAS(&rowown[ra0], -1, col0) == -1) p_l[col0] = ra0 + 1; }
  if (a1){ if (atomicCAS(&rowown[ra1], -1, col1) == -1) p_l[col1] = ra1 + 1; }
  __syncthreads();

  // free-row list
  bool f0 = (lane < k)    && (rowown[lane]    == -1);
  bool f1 = (lane+64 < k) && (rowown[lane+64] == -1);
  unsigned long long B0 = __ballot(f0), B1 = __ballot(f1);
  int n0 = __popcll(B0);
  if (f0) listA[__popcll(B0 & lm)]      = lane + 1;   // rows 1-based
  if (f1) listA[n0 + __popcll(B1 & lm)] = lane + 65;
  int nCur = n0 + __popcll(B1);
  __syncthreads();

  // ---- augmenting row reduction, 3 passes ----
  int* curL = listA; int* nxtL = listB;
  for (int pass = 0; pass < 3; pass++){
    int nNxt = 0;
    for (int fr = 0; fr < nCur; fr++){
      int row = curL[fr];                       // wave-uniform
      int off = (row - 1) * STRIDE;
      float rc0 = a0 ? (Cm[off + lane]      - v0) : INFINITY;
      float rc1 = a1 ? (Cm[off + 64 + lane] - v1) : INFINITY;
      unsigned k0 = fkey(rc0), k1 = fkey(rc1);
      unsigned kk = k0 < k1 ? k0 : k1;
      unsigned m1 = (unsigned)__builtin_amdgcn_readlane((int)dpp_min64(kk), 63);
      int cand = (k0 == m1) ? col0 : ((k1 == m1) ? col1 : 0);
      unsigned long long bl1 = __ballot(cand != 0);
      int ow1 = __ffsll(bl1) - 1;
      int j1 = __builtin_amdgcn_readlane(cand, ow1);
      float u1 = inv_fkey(m1);
      unsigned k0b = (col0 == j1) ? 0xFFFFFFFFu : k0;
      unsigned k1b = (col1 == j1) ? 0xFFFFFFFFu : k1;
      unsigned kkb = k0b < k1b ? k0b : k1b;
      unsigned m2 = (unsigned)__builtin_amdgcn_readlane((int)dpp_min64(kkb), 63);
      float u2 = inv_fkey(m2);
      int jt = j1;
      if (u1 < u2){
        if (col0 == j1) v0 -= (u2 - u1);
        if (col1 == j1) v1 -= (u2 - u1);
      } else {
        int own1 = p_l[j1];
        if (own1 != 0){
          int cand2 = (k0b == m2) ? col0 : ((k1b == m2) ? col1 : 0);
          unsigned long long bl2 = __ballot(cand2 != 0);
          int ow2 = __ffsll(bl2) - 1;
          jt = __builtin_amdgcn_readlane(cand2, ow2);
        }
      }
      int iprev = p_l[jt];                      // wave-uniform
      if (lane == 0){ p_l[jt] = row; u_l[row] = u2; }
      if (iprev != 0){ if (lane == 0) nxtL[nNxt] = iprev; nNxt++; }
      __syncthreads();
    }
    int* tmp = curL; curL = nxtL; nxtL = tmp;
    nCur = nNxt;
  }

  // ---- Dijkstra shortest augmenting path for remaining free rows ----
  for (int fr = 0; fr < nCur; fr++){
    int irow = curL[fr];
    int rp0 = a0 ? p_l[col0] : 0;
    int rp1 = a1 ? p_l[col1] : 0;
    float rpu0 = (rp0 > 0) ? u_l[rp0] : 0.f;
    float rpu1 = (rp1 > 0) ? u_l[rp1] : 0.f;
    int off = (irow - 1) * STRIDE;
    float dist0 = a0 ? (Cm[off + lane]      - v0) : INFINITY;
    float dist1 = a1 ? (Cm[off + 64 + lane] - v1) : INFINITY;
    int way0 = 0, way1 = 0;
    bool used0 = false, used1 = false;
    int j_end; float delta_end;
    while (true){
      unsigned q0 = (a0 && !used0) ? ((fkey(dist0) & 0xFFFFFF80u) | (unsigned)(col0-1)) : 0xFFFFFFFFu;
      unsigned q1 = (a1 && !used1) ? ((fkey(dist1) & 0xFFFFFF80u) | (unsigned)(col1-1)) : 0xFFFFFFFFu;
      unsigned key = q0 < q1 ? q0 : q1;
      unsigned kmin = (unsigned)__builtin_amdgcn_readlane((int)dpp_min64(key), 63);
      int j1 = (int)(kmin & 127u) + 1;
      int owner = (j1-1) & 63, slot = (j1-1) >> 6;   // wave-uniform (SGPR)
      float dsel  = slot ? dist1 : dist0;
      int   psel  = slot ? rp1   : rp0;
      float pusel = slot ? rpu1  : rpu0;
      // dynamic-SGPR readlane: exact broadcast, no DS latency
      float delta = __uint_as_float((unsigned)__builtin_amdgcn_readlane(__float_as_int(dsel), owner));
      int   i0    = __builtin_amdgcn_readlane(psel, owner);
      float pu    = __uint_as_float((unsigned)__builtin_amdgcn_readlane(__float_as_int(pusel), owner));
      used0 |= (j1 == col0);
      used1 |= (j1 == col1);
      if (i0 == 0){ j_end = j1; delta_end = delta; break; }
      float bse = delta - pu;
      int o2 = (i0 - 1) * STRIDE;
      float c0 = Cm[o2 + lane];
      float c1 = Cm[o2 + 64 + lane];
      float nd0 = bse + c0 - v0;
      float nd1 = bse + c1 - v1;
      if (a0 && !used0 && (nd0 < dist0)){ dist0 = nd0; way0 = j1; }
      if (a1 && !used1 && (nd1 < dist1)){ dist1 = nd1; way1 = j1; }
    }
    if (used0){ float adj = delta_end - dist0; v0 -= adj; u_l[rp0] = rpu0 + adj; }
    if (used1){ float adj = delta_end - dist1; v1 -= adj; u_l[rp1] = rpu1 + adj; }
    if (lane == 0) u_l[irow] = delta_end;
    if (a0) way_l[col0] = way0;
    if (a1) way_l[col1] = way1;
    __syncthreads();
    int j0 = j_end;
    while (true){
      int jw = way_l[j0];
      int pr = p_l[jw];
      int pw = (jw == 0) ? irow : pr;
      if (lane == 0) p_l[j0] = pw;
      if (jw == 0) break;
      j0 = jw;
    }
    __syncthreads();
  }

  __syncthreads();
  float acc = 0.f;
  if (a0) acc += Cm[(p_l[col0]-1)*STRIDE + lane];
  if (a1) acc += Cm[(p_l[col1]-1)*STRIDE + 64 + lane];
  acc = wave_sum(acc);
  if (lane == 0) gval[g] = -acc;       // max-assignment value of A
}

// ---------------------------------------------------------------------------
// loss = (sum lse - sum_g gval) / sum_g k   (unmasked rows hold lse=0)
__global__ __launch_bounds__(256) void k_final(const float* __restrict__ lse,
                                               const int* __restrict__ kcnt,
                                               const float* __restrict__ gval,
                                               float* __restrict__ out){
  __shared__ double sd[256];
  __shared__ double sg[256];
  __shared__ int    si[256];
  int tid = threadIdx.x;
  double s = 0.0, gs = 0.0; int c = 0;
  for (int i = tid; i < BB*NN; i += 256) s += (double)lse[i];
  for (int i = tid; i < NG; i += 256){ gs += (double)gval[i]; c += kcnt[i]; }
  sd[tid] = s; sg[tid] = gs; si[tid] = c;
  __syncthreads();
  for (int off = 128; off; off >>= 1){
    if (tid < off){ sd[tid] += sd[tid+off]; sg[tid] += sg[tid+off]; si[tid] += si[tid+off]; }
    __syncthreads();
  }
  if (tid == 0) out[0] = (float)((sd[0] - sg[0]) / (double)si[0]);
}

extern "C" void kernel_launch(void* const* d_in, const int* in_sizes, int n_in,
                              void* d_out, int out_size, void* d_ws, size_t ws_size,
                              hipStream_t stream) {
  const float* logits = (const float*)d_in[0];
  const int*   gt     = (const int*)d_in[1];
  const int*   types  = (const int*)d_in[2];
  const unsigned char* maskraw = (const unsigned char*)d_in[3];
  float* out = (float*)d_out;

  char* w = (char*)d_ws;
  float* lse  = (float*)w;  w += (size_t)BB*NN*4;
  int*   kcnt = (int*)w;    w += 1024;
  float* gval = (float*)w;  w += 1024;

  k_lse  <<<BB*NN, 256, 0, stream>>>(logits, maskraw, lse);
  k_jv   <<<NG,     64, 0, stream>>>(logits, types, gt, maskraw, kcnt, gval);
  k_final<<<1,     256, 0, stream>>>(lse, kcnt, gval, out);
}